// Round 1
// baseline (987.266 us; speedup 1.0000x reference)
//
#include <hip/hip_runtime.h>
#include <float.h>
#include <math.h>

#define N_NODES 50000
#define N_EDGES 400000
#define ETOT    (N_EDGES + N_NODES)   // 450000
#define F_IN    5
#define HEADS   8
#define C1      64
#define C2      32
#define C3      16
#define HC1     (HEADS * C1)          // 512
#define HC2     (HEADS * C2)          // 256
#define NEG_SLOPE 0.2f
#define NCHUNK  ((N_NODES + 255) / 256)  // 196

__device__ __forceinline__ void atomicMaxF(float* addr, float v) {
    if (v >= 0.f) atomicMax((int*)addr, __float_as_int(v));
    else          atomicMin((unsigned int*)addr, __float_as_uint(v));
}

__device__ __forceinline__ float eluf(float x) {
    return x > 0.f ? x : (expf(x) - 1.f);
}

// ---------------- init: zero counters, set m = -FLT_MAX ----------------
__global__ void k_init(int* degi, int* cursor, float* degf,
                       float* m1, float* den1, float* m2, float* den2) {
    int i = blockIdx.x * blockDim.x + threadIdx.x;
    if (i < N_NODES) { degi[i] = 0; cursor[i] = 0; degf[i] = 0.f; }
    if (i < N_NODES * HEADS) {
        m1[i] = -FLT_MAX; den1[i] = 0.f;
        m2[i] = -FLT_MAX; den2[i] = 0.f;
    }
}

// ---------------- degree histogram (int count + weighted for GCN) ------
__global__ void k_deg(const int* __restrict__ ei, const float* __restrict__ ew,
                      int* degi, float* degf) {
    int i = blockIdx.x * blockDim.x + threadIdx.x;
    if (i >= ETOT) return;
    int d   = (i < N_EDGES) ? ei[N_EDGES + i] : (i - N_EDGES);
    float w = (i < N_EDGES) ? ew[i] : 1.f;
    atomicAdd(&degi[d], 1);
    atomicAdd(&degf[d], w);
}

// ---------------- 3-kernel exclusive scan over deg[N] ------------------
__global__ void k_scan_a(const int* __restrict__ deg, int* __restrict__ part) {
    __shared__ int lds[256];
    int t = threadIdx.x;
    int i = blockIdx.x * 256 + t;
    lds[t] = (i < N_NODES) ? deg[i] : 0;
    __syncthreads();
    for (int off = 128; off >= 1; off >>= 1) {
        if (t < off) lds[t] += lds[t + off];
        __syncthreads();
    }
    if (t == 0) part[blockIdx.x] = lds[0];
}

__global__ void k_scan_b(int* part) {   // in-place exclusive scan of part[NCHUNK]
    __shared__ int lds[256];
    int t = threadIdx.x;
    int v = (t < NCHUNK) ? part[t] : 0;
    lds[t] = v;
    __syncthreads();
    for (int off = 1; off < 256; off <<= 1) {
        int x = (t >= off) ? lds[t - off] : 0;
        __syncthreads();
        lds[t] += x;
        __syncthreads();
    }
    if (t < NCHUNK) part[t] = lds[t] - v;
}

__global__ void k_scan_c(const int* __restrict__ deg, const int* __restrict__ part,
                         int* __restrict__ offs) {
    __shared__ int lds[256];
    int t = threadIdx.x;
    int i = blockIdx.x * 256 + t;
    int v = (i < N_NODES) ? deg[i] : 0;
    lds[t] = v;
    __syncthreads();
    for (int off = 1; off < 256; off <<= 1) {
        int x = (t >= off) ? lds[t - off] : 0;
        __syncthreads();
        lds[t] += x;
        __syncthreads();
    }
    int excl = part[blockIdx.x] + lds[t] - v;
    if (i < N_NODES) offs[i] = excl;
    if (i == N_NODES - 1) offs[N_NODES] = excl + v;
}

// ---------------- scatter edges into CSR-by-dst ------------------------
__global__ void k_scatter(const int* __restrict__ ei, const int* __restrict__ offs,
                          int* cursor, int* __restrict__ csr_src, int* __restrict__ csr_eid) {
    int i = blockIdx.x * blockDim.x + threadIdx.x;
    if (i >= ETOT) return;
    int s, d;
    if (i < N_EDGES) { s = ei[i]; d = ei[N_EDGES + i]; }
    else             { s = d = i - N_EDGES; }
    int pos = offs[d] + atomicAdd(&cursor[d], 1);
    csr_src[pos] = s;
    csr_eid[pos] = i;
}

// ---------------- layer 1: h1 = x@W1 fused with es/ed reductions -------
__global__ __launch_bounds__(512) void k_h1(const float* __restrict__ x,
                                            const float* __restrict__ W1,
                                            const float* __restrict__ a_src,
                                            const float* __restrict__ a_dst,
                                            float* __restrict__ h1,
                                            float* __restrict__ es,
                                            float* __restrict__ ed) {
    int n = blockIdx.x;
    int t = threadIdx.x;           // t = h*64 + c
    float xv[F_IN];
#pragma unroll
    for (int f = 0; f < F_IN; f++) xv[f] = x[n * F_IN + f];
    float acc = 0.f;
#pragma unroll
    for (int f = 0; f < F_IN; f++) acc += xv[f] * W1[f * HC1 + t];
    h1[(size_t)n * HC1 + t] = acc;
    float vs = acc * a_src[t];
    float vd = acc * a_dst[t];
#pragma unroll
    for (int off = 32; off >= 1; off >>= 1) {
        vs += __shfl_xor(vs, off, 64);
        vd += __shfl_xor(vd, off, 64);
    }
    if ((t & 63) == 0) {
        int h = t >> 6;
        es[n * HEADS + h] = vs;
        ed[n * HEADS + h] = vd;
    }
}

// ---------------- per-edge attention logits + segment max --------------
__global__ void k_edge_logits(const int* __restrict__ ei,
                              const float* __restrict__ es, const float* __restrict__ ed,
                              float* __restrict__ ebuf, float* m) {
    int g = blockIdx.x * blockDim.x + threadIdx.x;
    if (g >= ETOT * HEADS) return;
    int i = g >> 3, h = g & 7;
    int s, d;
    if (i < N_EDGES) { s = ei[i]; d = ei[N_EDGES + i]; }
    else             { s = d = i - N_EDGES; }
    float v = es[s * HEADS + h] + ed[d * HEADS + h];
    v = v > 0.f ? v : NEG_SLOPE * v;
    ebuf[g] = v;
    atomicMaxF(&m[d * HEADS + h], v);
}

// ---------------- per-edge exp + segment sum ---------------------------
__global__ void k_edge_exp(const int* __restrict__ ei, const float* __restrict__ m,
                           float* __restrict__ ebuf, float* den) {
    int g = blockIdx.x * blockDim.x + threadIdx.x;
    if (g >= ETOT * HEADS) return;
    int i = g >> 3, h = g & 7;
    int d = (i < N_EDGES) ? ei[N_EDGES + i] : (i - N_EDGES);
    float ex = expf(ebuf[g] - m[d * HEADS + h]);
    ebuf[g] = ex;
    atomicAdd(&den[d * HEADS + h], ex);
}

// ---------------- GAT aggregation (CSR gather) + bias + ELU ------------
template <int C>
__global__ void k_gat_agg(const float* __restrict__ hin, const float* __restrict__ ebuf,
                          const float* __restrict__ den,
                          const int* __restrict__ offs, const int* __restrict__ csr_src,
                          const int* __restrict__ csr_eid,
                          const float* __restrict__ bias, float* __restrict__ xout) {
    const int HC = HEADS * C;
    int d = blockIdx.x;
    int t = threadIdx.x;           // t = h*C + c
    int h = t / C;
    float invden = 1.f / (den[d * HEADS + h] + 1e-16f);
    int k0 = offs[d], k1 = offs[d + 1];
    float acc = 0.f;
    for (int k = k0; k < k1; k++) {
        int s   = csr_src[k];
        int eid = csr_eid[k];
        float alpha = ebuf[eid * HEADS + h] * invden;
        acc += hin[(size_t)s * HC + t] * alpha;
    }
    xout[(size_t)d * HC + t] = eluf(acc + bias[t]);
}

// ---------------- es/ed for layer 2 ------------------------------------
template <int C>
__global__ void k_es_ed(const float* __restrict__ hin,
                        const float* __restrict__ a_src, const float* __restrict__ a_dst,
                        float* __restrict__ es, float* __restrict__ ed) {
    int g = blockIdx.x * blockDim.x + threadIdx.x;
    if (g >= N_NODES * HEADS) return;
    int n = g >> 3, h = g & 7;
    const float* hp = hin + (size_t)n * HEADS * C + h * C;
    float vs = 0.f, vd = 0.f;
#pragma unroll 4
    for (int c = 0; c < C; c++) {
        float v = hp[c];
        vs += v * a_src[h * C + c];
        vd += v * a_dst[h * C + c];
    }
    es[g] = vs;
    ed[g] = vd;
}

// ---------------- tiled fp32 GEMM: C[M,Nn] = A[M,K] @ B[K,Nn] ----------
#define BM 64
#define BN 64
#define BK 16
__global__ __launch_bounds__(256) void k_gemm(const float* __restrict__ A,
                                              const float* __restrict__ B,
                                              float* __restrict__ C,
                                              int M, int Nn, int K) {
    __shared__ float As[BK][BM + 1];
    __shared__ float Bs[BK][BN];
    int col0 = blockIdx.x * BN;
    int row0 = blockIdx.y * BM;
    int t  = threadIdx.x;
    int tx = t & 15, ty = t >> 4;
    float acc[4][4] = {};
    for (int k0 = 0; k0 < K; k0 += BK) {
        {   // A tile 64x16: thread t -> row m=t/4, 4 consecutive k
            int m  = t >> 2, kq = t & 3;
            float4 v = make_float4(0.f, 0.f, 0.f, 0.f);
            if (row0 + m < M)
                v = *(const float4*)(A + (size_t)(row0 + m) * K + k0 + kq * 4);
            As[kq * 4 + 0][m] = v.x;
            As[kq * 4 + 1][m] = v.y;
            As[kq * 4 + 2][m] = v.z;
            As[kq * 4 + 3][m] = v.w;
        }
        {   // B tile 16x64: thread t -> k=t/16, 4 consecutive n
            int kk = t >> 4, nq = t & 15;
            float4 v = *(const float4*)(B + (size_t)(k0 + kk) * Nn + col0 + nq * 4);
            Bs[kk][nq * 4 + 0] = v.x;
            Bs[kk][nq * 4 + 1] = v.y;
            Bs[kk][nq * 4 + 2] = v.z;
            Bs[kk][nq * 4 + 3] = v.w;
        }
        __syncthreads();
#pragma unroll
        for (int k = 0; k < BK; k++) {
            float a[4], b[4];
#pragma unroll
            for (int i = 0; i < 4; i++) a[i] = As[k][ty * 4 + i];
#pragma unroll
            for (int j = 0; j < 4; j++) b[j] = Bs[k][tx * 4 + j];
#pragma unroll
            for (int i = 0; i < 4; i++)
#pragma unroll
                for (int j = 0; j < 4; j++) acc[i][j] += a[i] * b[j];
        }
        __syncthreads();
    }
#pragma unroll
    for (int i = 0; i < 4; i++) {
        int r = row0 + ty * 4 + i;
        if (r >= M) continue;
#pragma unroll
        for (int j = 0; j < 4; j++)
            C[(size_t)r * Nn + col0 + tx * 4 + j] = acc[i][j];
    }
}

// ---------------- hg = x3 @ Wg  (N,256)@(256,16) -----------------------
__global__ __launch_bounds__(256) void k_hg(const float* __restrict__ x3,
                                            const float* __restrict__ Wg,
                                            float* __restrict__ hg) {
    __shared__ float xs[16 * HC2];
    int n0 = blockIdx.x * 16;
    int t  = threadIdx.x;
    for (int idx = t; idx < 16 * HC2; idx += 256) {
        int r = idx / HC2, c = idx % HC2;
        int n = n0 + r;
        xs[idx] = (n < N_NODES) ? x3[(size_t)n * HC2 + c] : 0.f;
    }
    __syncthreads();
    int r = t >> 4, c = t & 15;
    float acc = 0.f;
#pragma unroll 4
    for (int k = 0; k < HC2; k++) acc += xs[r * HC2 + k] * Wg[k * C3 + c];
    int n = n0 + r;
    if (n < N_NODES) hg[(size_t)n * C3 + c] = acc;
}

// ---------------- GCN aggregate + ELU + FC + sigmoid (fused) -----------
__global__ __launch_bounds__(256) void k_gcn_out(const float* __restrict__ hg,
                                                 const float* __restrict__ ew,
                                                 const float* __restrict__ degf,
                                                 const int* __restrict__ offs,
                                                 const int* __restrict__ csr_src,
                                                 const int* __restrict__ csr_eid,
                                                 const float* __restrict__ bg,
                                                 const float* __restrict__ Wfc,
                                                 const float* __restrict__ bfc,
                                                 float* __restrict__ out) {
    int t = threadIdx.x;
    int r = t >> 4, c = t & 15;
    int d = blockIdx.x * 16 + r;
    float val = 0.f;
    if (d < N_NODES) {
        float dd = degf[d];
        float dinv_d = dd > 0.f ? rsqrtf(dd) : 0.f;
        int k0 = offs[d], k1 = offs[d + 1];
        float acc = 0.f;
        for (int k = k0; k < k1; k++) {
            int s   = csr_src[k];
            int eid = csr_eid[k];
            float w = (eid < N_EDGES) ? ew[eid] : 1.f;
            float ds_ = degf[s];
            float dinv_s = ds_ > 0.f ? rsqrtf(ds_) : 0.f;
            acc += hg[(size_t)s * C3 + c] * (dinv_s * w * dinv_d);
        }
        val = eluf(acc + bg[c]);
    }
    float z = val * Wfc[c];
#pragma unroll
    for (int off = 8; off >= 1; off >>= 1) z += __shfl_xor(z, off, 16);
    if (c == 0 && d < N_NODES) out[d] = 1.f / (1.f + expf(-(z + bfc[0])));
}

// =======================================================================
extern "C" void kernel_launch(void* const* d_in, const int* in_sizes, int n_in,
                              void* d_out, int out_size, void* d_ws, size_t ws_size,
                              hipStream_t stream) {
    const float* x       = (const float*)d_in[0];
    const int*   ei      = (const int*)  d_in[1];
    const float* ew      = (const float*)d_in[2];
    const float* W1      = (const float*)d_in[3];
    const float* a_src1  = (const float*)d_in[4];
    const float* a_dst1  = (const float*)d_in[5];
    const float* b1      = (const float*)d_in[6];
    const float* W2      = (const float*)d_in[7];
    const float* a_src2  = (const float*)d_in[8];
    const float* a_dst2  = (const float*)d_in[9];
    const float* b2      = (const float*)d_in[10];
    const float* Wg      = (const float*)d_in[11];
    const float* bg      = (const float*)d_in[12];
    const float* Wfc     = (const float*)d_in[13];
    const float* bfc     = (const float*)d_in[14];
    float* out = (float*)d_out;

    char* w = (char*)d_ws;
    size_t off = 0;
    auto alloc = [&](size_t bytes) -> void* {
        void* p = w + off;
        off = (off + bytes + 255) & ~(size_t)255;
        return p;
    };
    float* bufA   = (float*)alloc((size_t)N_NODES * HC1 * 4);  // h1; then h2 (first half) + x3 (second half)
    float* bufB   = (float*)alloc((size_t)N_NODES * HC1 * 4);  // x2; then hg
    float* ebuf   = (float*)alloc((size_t)ETOT * HEADS * 4);
    float* es1    = (float*)alloc((size_t)N_NODES * HEADS * 4);
    float* ed1    = (float*)alloc((size_t)N_NODES * HEADS * 4);
    float* m1     = (float*)alloc((size_t)N_NODES * HEADS * 4);
    float* den1   = (float*)alloc((size_t)N_NODES * HEADS * 4);
    float* es2    = (float*)alloc((size_t)N_NODES * HEADS * 4);
    float* ed2    = (float*)alloc((size_t)N_NODES * HEADS * 4);
    float* m2     = (float*)alloc((size_t)N_NODES * HEADS * 4);
    float* den2   = (float*)alloc((size_t)N_NODES * HEADS * 4);
    float* degf   = (float*)alloc((size_t)N_NODES * 4);
    int*   degi   = (int*)  alloc((size_t)N_NODES * 4);
    int*   cursor = (int*)  alloc((size_t)N_NODES * 4);
    int*   offs   = (int*)  alloc((size_t)(N_NODES + 1) * 4);
    int*   part   = (int*)  alloc(256 * 4);
    int*   csr_src= (int*)  alloc((size_t)ETOT * 4);
    int*   csr_eid= (int*)  alloc((size_t)ETOT * 4);

    float* h1 = bufA;
    float* x2 = bufB;
    float* h2 = bufA;                              // N*256, reuses h1 space
    float* x3 = bufA + (size_t)N_NODES * HC2;      // N*256, second half of bufA
    float* hg = bufB;                              // N*16, reuses x2 space

    const int T = 256;
    // ---- CSR build + init ----
    k_init<<<dim3((N_NODES * HEADS + T - 1) / T), dim3(T), 0, stream>>>(
        degi, cursor, degf, m1, den1, m2, den2);
    k_deg<<<dim3((ETOT + T - 1) / T), dim3(T), 0, stream>>>(ei, ew, degi, degf);
    k_scan_a<<<dim3(NCHUNK), dim3(256), 0, stream>>>(degi, part);
    k_scan_b<<<dim3(1), dim3(256), 0, stream>>>(part);
    k_scan_c<<<dim3(NCHUNK), dim3(256), 0, stream>>>(degi, part, offs);
    k_scatter<<<dim3((ETOT + T - 1) / T), dim3(T), 0, stream>>>(ei, offs, cursor, csr_src, csr_eid);

    // ---- GAT layer 1 ----
    k_h1<<<dim3(N_NODES), dim3(HC1), 0, stream>>>(x, W1, a_src1, a_dst1, h1, es1, ed1);
    k_edge_logits<<<dim3((ETOT * HEADS + T - 1) / T), dim3(T), 0, stream>>>(ei, es1, ed1, ebuf, m1);
    k_edge_exp<<<dim3((ETOT * HEADS + T - 1) / T), dim3(T), 0, stream>>>(ei, m1, ebuf, den1);
    k_gat_agg<C1><<<dim3(N_NODES), dim3(HC1), 0, stream>>>(h1, ebuf, den1, offs, csr_src, csr_eid, b1, x2);

    // ---- GAT layer 2 ----
    k_gemm<<<dim3(HC2 / BN, (N_NODES + BM - 1) / BM), dim3(256), 0, stream>>>(
        x2, W2, h2, N_NODES, HC2, HC1);
    k_es_ed<C2><<<dim3((N_NODES * HEADS + T - 1) / T), dim3(T), 0, stream>>>(h2, a_src2, a_dst2, es2, ed2);
    k_edge_logits<<<dim3((ETOT * HEADS + T - 1) / T), dim3(T), 0, stream>>>(ei, es2, ed2, ebuf, m2);
    k_edge_exp<<<dim3((ETOT * HEADS + T - 1) / T), dim3(T), 0, stream>>>(ei, m2, ebuf, den2);
    k_gat_agg<C2><<<dim3(N_NODES), dim3(HC2), 0, stream>>>(h2, ebuf, den2, offs, csr_src, csr_eid, b2, x3);

    // ---- GCN + FC + sigmoid ----
    k_hg<<<dim3((N_NODES + 15) / 16), dim3(256), 0, stream>>>(x3, Wg, hg);
    k_gcn_out<<<dim3((N_NODES + 15) / 16), dim3(256), 0, stream>>>(
        hg, ew, degf, offs, csr_src, csr_eid, bg, Wfc, bfc, out);
}

// Round 2
// 623.728 us; speedup vs baseline: 1.5828x; 1.5828x over previous
//
#include <hip/hip_runtime.h>
#include <hip/hip_bf16.h>
#include <float.h>
#include <math.h>

#define N_NODES 50000
#define N_EDGES 400000
#define ETOT    (N_EDGES + N_NODES)   // 450000
#define F_IN    5
#define HEADS   8
#define C1      64
#define C2      32
#define C3      16
#define HC1     (HEADS * C1)          // 512
#define HC2     (HEADS * C2)          // 256
#define NEG_SLOPE 0.2f
#define NCHUNK  ((N_NODES + 255) / 256)  // 196
#define NH8     (N_NODES * HEADS)        // 400000
#define MPAD    (((N_NODES + 63) / 64) * 64)  // 50048 rows for MFMA GEMM

typedef short bf16x8 __attribute__((ext_vector_type(8)));
typedef float f32x4  __attribute__((ext_vector_type(4)));

__device__ __forceinline__ float eluf(float x) {
    return x > 0.f ? x : (expf(x) - 1.f);
}

// ---------------- init: zero counters/denominators ---------------------
__global__ void k_init(int* degi, int* cursor, float* degf,
                       float* den1, float* den2) {
    int i = blockIdx.x * blockDim.x + threadIdx.x;
    if (i < N_NODES) { degi[i] = 0; cursor[i] = 0; degf[i] = 0.f; }
    if (i < NH8) { den1[i] = 0.f; den2[i] = 0.f; }
}

// ---------------- degree histogram (int count + weighted for GCN) ------
__global__ void k_deg(const int* __restrict__ ei, const float* __restrict__ ew,
                      int* degi, float* degf) {
    int i = blockIdx.x * blockDim.x + threadIdx.x;
    if (i >= ETOT) return;
    int d   = (i < N_EDGES) ? ei[N_EDGES + i] : (i - N_EDGES);
    float w = (i < N_EDGES) ? ew[i] : 1.f;
    atomicAdd(&degi[d], 1);
    atomicAdd(&degf[d], w);
}

// ---------------- 3-kernel exclusive scan over deg[N] ------------------
__global__ void k_scan_a(const int* __restrict__ deg, int* __restrict__ part) {
    __shared__ int lds[256];
    int t = threadIdx.x;
    int i = blockIdx.x * 256 + t;
    lds[t] = (i < N_NODES) ? deg[i] : 0;
    __syncthreads();
    for (int off = 128; off >= 1; off >>= 1) {
        if (t < off) lds[t] += lds[t + off];
        __syncthreads();
    }
    if (t == 0) part[blockIdx.x] = lds[0];
}

__global__ void k_scan_b(int* part) {   // in-place exclusive scan of part[NCHUNK]
    __shared__ int lds[256];
    int t = threadIdx.x;
    int v = (t < NCHUNK) ? part[t] : 0;
    lds[t] = v;
    __syncthreads();
    for (int off = 1; off < 256; off <<= 1) {
        int x = (t >= off) ? lds[t - off] : 0;
        __syncthreads();
        lds[t] += x;
        __syncthreads();
    }
    if (t < NCHUNK) part[t] = lds[t] - v;
}

__global__ void k_scan_c(const int* __restrict__ deg, const int* __restrict__ part,
                         int* __restrict__ offs) {
    __shared__ int lds[256];
    int t = threadIdx.x;
    int i = blockIdx.x * 256 + t;
    int v = (i < N_NODES) ? deg[i] : 0;
    lds[t] = v;
    __syncthreads();
    for (int off = 1; off < 256; off <<= 1) {
        int x = (t >= off) ? lds[t - off] : 0;
        __syncthreads();
        lds[t] += x;
        __syncthreads();
    }
    int excl = part[blockIdx.x] + lds[t] - v;
    if (i < N_NODES) offs[i] = excl;
    if (i == N_NODES - 1) offs[N_NODES] = excl + v;
}

// ---------------- scatter edges into CSR-by-dst ------------------------
__global__ void k_scatter(const int* __restrict__ ei, const int* __restrict__ offs,
                          int* cursor, int* __restrict__ csr_src, int* __restrict__ csr_eid) {
    int i = blockIdx.x * blockDim.x + threadIdx.x;
    if (i >= ETOT) return;
    int s, d;
    if (i < N_EDGES) { s = ei[i]; d = ei[N_EDGES + i]; }
    else             { s = d = i - N_EDGES; }
    int pos = offs[d] + atomicAdd(&cursor[d], 1);
    csr_src[pos] = s;
    csr_eid[pos] = i;
}

// ---------------- fold W1 into attention vectors: as1f[h,f] ------------
__global__ void k_fold(const float* __restrict__ W1,
                       const float* __restrict__ a_src1, const float* __restrict__ a_dst1,
                       float* __restrict__ as1f, float* __restrict__ ad1f) {
    int idx = threadIdx.x;
    if (idx >= HEADS * F_IN) return;
    int h = idx / F_IN, f = idx % F_IN;
    float s = 0.f, d = 0.f;
    for (int c = 0; c < C1; c++) {
        float w = W1[f * HC1 + h * C1 + c];
        s += w * a_src1[h * C1 + c];
        d += w * a_dst1[h * C1 + c];
    }
    as1f[idx] = s;
    ad1f[idx] = d;
}

// ---------------- es1/ed1 directly from x ------------------------------
__global__ void k_es1(const float* __restrict__ x,
                      const float* __restrict__ as1f, const float* __restrict__ ad1f,
                      float* __restrict__ es, float* __restrict__ ed) {
    int g = blockIdx.x * blockDim.x + threadIdx.x;
    if (g >= NH8) return;
    int n = g >> 3, h = g & 7;
    float vs = 0.f, vd = 0.f;
#pragma unroll
    for (int f = 0; f < F_IN; f++) {
        float xv = x[n * F_IN + f];
        vs += xv * as1f[h * F_IN + f];
        vd += xv * ad1f[h * F_IN + f];
    }
    es[g] = vs;
    ed[g] = vd;
}

// -------- fused edge softmax numerator: ex=exp(leaky(es+ed)), den += ex
__global__ void k_edge_soft(const int* __restrict__ ei,
                            const float* __restrict__ es, const float* __restrict__ ed,
                            float* __restrict__ ebuf, float* den) {
    int g = blockIdx.x * blockDim.x + threadIdx.x;
    if (g >= ETOT * HEADS) return;
    int i = g >> 3, h = g & 7;
    int s, d;
    if (i < N_EDGES) { s = ei[i]; d = ei[N_EDGES + i]; }
    else             { s = d = i - N_EDGES; }
    float v = es[s * HEADS + h] + ed[d * HEADS + h];
    v = v > 0.f ? v : NEG_SLOPE * v;
    float ex = expf(v);
    ebuf[g] = ex;
    atomicAdd(&den[d * HEADS + h], ex);
}

// -------- layer-1 aggregation of raw x (5 feats) per (dst, head) -------
__global__ void k_agg_x(const float* __restrict__ x, const float* __restrict__ ebuf,
                        const float* __restrict__ den,
                        const int* __restrict__ offs, const int* __restrict__ csr_src,
                        const int* __restrict__ csr_eid,
                        float* __restrict__ aggx) {
    int g = blockIdx.x * blockDim.x + threadIdx.x;
    if (g >= NH8) return;
    int d = g >> 3, h = g & 7;
    int k0 = offs[d], k1 = offs[d + 1];
    float a0 = 0.f, a1 = 0.f, a2 = 0.f, a3 = 0.f, a4 = 0.f;
    for (int k = k0; k < k1; k++) {
        int s   = csr_src[k];
        int eid = csr_eid[k];
        float ex = ebuf[eid * HEADS + h];
        const float* xp = x + s * F_IN;
        a0 += ex * xp[0];
        a1 += ex * xp[1];
        a2 += ex * xp[2];
        a3 += ex * xp[3];
        a4 += ex * xp[4];
    }
    float inv = 1.f / (den[g] + 1e-16f);
    aggx[0 * NH8 + g] = a0 * inv;
    aggx[1 * NH8 + g] = a1 * inv;
    aggx[2 * NH8 + g] = a2 * inv;
    aggx[3 * NH8 + g] = a3 * inv;
    aggx[4 * NH8 + g] = a4 * inv;
}

// -------- expand aggx (N,8,5) @ W1 -> x2 = elu(. + b1), store bf16 -----
__global__ __launch_bounds__(512) void k_expand(const float* __restrict__ aggx,
                                                const float* __restrict__ W1,
                                                const float* __restrict__ b1,
                                                __hip_bfloat16* __restrict__ x2bf) {
    int d = blockIdx.x;
    int t = threadIdx.x;       // t = h*64 + c
    int h = t >> 6;
    int g = d * HEADS + h;
    float acc = b1[t];
#pragma unroll
    for (int f = 0; f < F_IN; f++)
        acc += aggx[f * NH8 + g] * W1[f * HC1 + t];
    acc = eluf(acc);
    x2bf[(size_t)d * HC1 + t] = __float2bfloat16(acc);
}

// ---------------- pack W2 (512x256 f32) -> W2T (256x512 bf16) ----------
__global__ void k_packW2(const float* __restrict__ W2, __hip_bfloat16* __restrict__ W2T) {
    int idx = blockIdx.x * blockDim.x + threadIdx.x;
    if (idx >= HC1 * HC2) return;
    int k = idx / HC2, n = idx % HC2;
    W2T[(size_t)n * HC1 + k] = __float2bfloat16(W2[idx]);
}

// ---------------- bf16 MFMA GEMM: h2[M,256] = x2bf[M,512] @ W2T^T ------
// A-frag: A[m=lane&15][k=quad*8+j]; B-frag: B'[n=lane&15][k=quad*8+j];
// D: col=lane&15, row=quad*4+reg  (verified gfx950 layouts)
__global__ __launch_bounds__(256) void k_gemm_mfma(const short* __restrict__ A,
                                                   const short* __restrict__ B,
                                                   float* __restrict__ C) {
    int wave = threadIdx.x >> 6;
    int lane = threadIdx.x & 63;
    int lo   = lane & 15;
    int quad = lane >> 4;
    int m0   = blockIdx.x * 64 + wave * 16;
    int col0 = blockIdx.y * 64;
    const short* ap = A + (size_t)(m0 + lo) * HC1 + quad * 8;
    const short* bp = B + (size_t)(col0 + lo) * HC1 + quad * 8;
    f32x4 acc0 = {0.f, 0.f, 0.f, 0.f};
    f32x4 acc1 = {0.f, 0.f, 0.f, 0.f};
    f32x4 acc2 = {0.f, 0.f, 0.f, 0.f};
    f32x4 acc3 = {0.f, 0.f, 0.f, 0.f};
#pragma unroll
    for (int k0 = 0; k0 < HC1; k0 += 32) {
        bf16x8 af = *(const bf16x8*)(ap + k0);
        bf16x8 b0 = *(const bf16x8*)(bp + 0 * 16 * HC1 + k0);
        bf16x8 b1 = *(const bf16x8*)(bp + 1 * 16 * HC1 + k0);
        bf16x8 b2 = *(const bf16x8*)(bp + 2 * 16 * HC1 + k0);
        bf16x8 b3 = *(const bf16x8*)(bp + 3 * 16 * HC1 + k0);
        acc0 = __builtin_amdgcn_mfma_f32_16x16x32_bf16(af, b0, acc0, 0, 0, 0);
        acc1 = __builtin_amdgcn_mfma_f32_16x16x32_bf16(af, b1, acc1, 0, 0, 0);
        acc2 = __builtin_amdgcn_mfma_f32_16x16x32_bf16(af, b2, acc2, 0, 0, 0);
        acc3 = __builtin_amdgcn_mfma_f32_16x16x32_bf16(af, b3, acc3, 0, 0, 0);
    }
    int colw = col0 + lo;
#pragma unroll
    for (int r = 0; r < 4; r++) {
        int row = m0 + quad * 4 + r;
        if (row < N_NODES) {
            C[(size_t)row * HC2 + colw +  0] = acc0[r];
            C[(size_t)row * HC2 + colw + 16] = acc1[r];
            C[(size_t)row * HC2 + colw + 32] = acc2[r];
            C[(size_t)row * HC2 + colw + 48] = acc3[r];
        }
    }
}

// ---------------- es/ed for layer 2 ------------------------------------
template <int C>
__global__ void k_es_ed(const float* __restrict__ hin,
                        const float* __restrict__ a_src, const float* __restrict__ a_dst,
                        float* __restrict__ es, float* __restrict__ ed) {
    int g = blockIdx.x * blockDim.x + threadIdx.x;
    if (g >= NH8) return;
    int n = g >> 3, h = g & 7;
    const float* hp = hin + (size_t)n * HEADS * C + h * C;
    float vs = 0.f, vd = 0.f;
#pragma unroll 4
    for (int c = 0; c < C; c++) {
        float v = hp[c];
        vs += v * a_src[h * C + c];
        vd += v * a_dst[h * C + c];
    }
    es[g] = vs;
    ed[g] = vd;
}

// ---------------- GAT aggregation (CSR gather) + bias + ELU ------------
template <int C>
__global__ void k_gat_agg(const float* __restrict__ hin, const float* __restrict__ ebuf,
                          const float* __restrict__ den,
                          const int* __restrict__ offs, const int* __restrict__ csr_src,
                          const int* __restrict__ csr_eid,
                          const float* __restrict__ bias, float* __restrict__ xout) {
    const int HC = HEADS * C;
    int d = blockIdx.x;
    int t = threadIdx.x;           // t = h*C + c
    int h = t / C;
    float invden = 1.f / (den[d * HEADS + h] + 1e-16f);
    int k0 = offs[d], k1 = offs[d + 1];
    float acc = 0.f;
    for (int k = k0; k < k1; k++) {
        int s   = csr_src[k];
        int eid = csr_eid[k];
        float alpha = ebuf[eid * HEADS + h] * invden;
        acc += hin[(size_t)s * HC + t] * alpha;
    }
    xout[(size_t)d * HC + t] = eluf(acc + bias[t]);
}

// ---------------- hg = x3 @ Wg  (N,256)@(256,16) -----------------------
__global__ __launch_bounds__(256) void k_hg(const float* __restrict__ x3,
                                            const float* __restrict__ Wg,
                                            float* __restrict__ hg) {
    __shared__ float xs[16 * HC2];
    int n0 = blockIdx.x * 16;
    int t  = threadIdx.x;
    for (int idx = t; idx < 16 * HC2; idx += 256) {
        int r = idx / HC2, c = idx % HC2;
        int n = n0 + r;
        xs[idx] = (n < N_NODES) ? x3[(size_t)n * HC2 + c] : 0.f;
    }
    __syncthreads();
    int r = t >> 4, c = t & 15;
    float acc = 0.f;
#pragma unroll 4
    for (int k = 0; k < HC2; k++) acc += xs[r * HC2 + k] * Wg[k * C3 + c];
    int n = n0 + r;
    if (n < N_NODES) hg[(size_t)n * C3 + c] = acc;
}

// ---------------- GCN aggregate + ELU + FC + sigmoid (fused) -----------
__global__ __launch_bounds__(256) void k_gcn_out(const float* __restrict__ hg,
                                                 const float* __restrict__ ew,
                                                 const float* __restrict__ degf,
                                                 const int* __restrict__ offs,
                                                 const int* __restrict__ csr_src,
                                                 const int* __restrict__ csr_eid,
                                                 const float* __restrict__ bg,
                                                 const float* __restrict__ Wfc,
                                                 const float* __restrict__ bfc,
                                                 float* __restrict__ out) {
    int t = threadIdx.x;
    int r = t >> 4, c = t & 15;
    int d = blockIdx.x * 16 + r;
    float val = 0.f;
    if (d < N_NODES) {
        float dd = degf[d];
        float dinv_d = dd > 0.f ? rsqrtf(dd) : 0.f;
        int k0 = offs[d], k1 = offs[d + 1];
        float acc = 0.f;
        for (int k = k0; k < k1; k++) {
            int s   = csr_src[k];
            int eid = csr_eid[k];
            float w = (eid < N_EDGES) ? ew[eid] : 1.f;
            float ds_ = degf[s];
            float dinv_s = ds_ > 0.f ? rsqrtf(ds_) : 0.f;
            acc += hg[(size_t)s * C3 + c] * (dinv_s * w * dinv_d);
        }
        val = eluf(acc + bg[c]);
    }
    float z = val * Wfc[c];
#pragma unroll
    for (int off = 8; off >= 1; off >>= 1) z += __shfl_xor(z, off, 16);
    if (c == 0 && d < N_NODES) out[d] = 1.f / (1.f + expf(-(z + bfc[0])));
}

// =======================================================================
extern "C" void kernel_launch(void* const* d_in, const int* in_sizes, int n_in,
                              void* d_out, int out_size, void* d_ws, size_t ws_size,
                              hipStream_t stream) {
    const float* x       = (const float*)d_in[0];
    const int*   ei      = (const int*)  d_in[1];
    const float* ew      = (const float*)d_in[2];
    const float* W1      = (const float*)d_in[3];
    const float* a_src1  = (const float*)d_in[4];
    const float* a_dst1  = (const float*)d_in[5];
    const float* b1      = (const float*)d_in[6];
    const float* W2      = (const float*)d_in[7];
    const float* a_src2  = (const float*)d_in[8];
    const float* a_dst2  = (const float*)d_in[9];
    const float* b2      = (const float*)d_in[10];
    const float* Wg      = (const float*)d_in[11];
    const float* bg      = (const float*)d_in[12];
    const float* Wfc     = (const float*)d_in[13];
    const float* bfc     = (const float*)d_in[14];
    float* out = (float*)d_out;

    char* w = (char*)d_ws;
    size_t off = 0;
    auto alloc = [&](size_t bytes) -> void* {
        void* p = w + off;
        off = (off + bytes + 255) & ~(size_t)255;
        return p;
    };
    __hip_bfloat16* x2bf = (__hip_bfloat16*)alloc((size_t)MPAD * HC1 * 2);
    __hip_bfloat16* W2T  = (__hip_bfloat16*)alloc((size_t)HC2 * HC1 * 2);
    float* h2     = (float*)alloc((size_t)N_NODES * HC2 * 4);
    float* x3     = (float*)alloc((size_t)N_NODES * HC2 * 4);
    float* hg     = (float*)alloc((size_t)N_NODES * C3 * 4);
    float* ebuf   = (float*)alloc((size_t)ETOT * HEADS * 4);
    float* aggx   = (float*)alloc((size_t)F_IN * NH8 * 4);
    float* es1    = (float*)alloc((size_t)NH8 * 4);
    float* ed1    = (float*)alloc((size_t)NH8 * 4);
    float* den1   = (float*)alloc((size_t)NH8 * 4);
    float* es2    = (float*)alloc((size_t)NH8 * 4);
    float* ed2    = (float*)alloc((size_t)NH8 * 4);
    float* den2   = (float*)alloc((size_t)NH8 * 4);
    float* as1f   = (float*)alloc((size_t)HEADS * F_IN * 4);
    float* ad1f   = (float*)alloc((size_t)HEADS * F_IN * 4);
    float* degf   = (float*)alloc((size_t)N_NODES * 4);
    int*   degi   = (int*)  alloc((size_t)N_NODES * 4);
    int*   cursor = (int*)  alloc((size_t)N_NODES * 4);
    int*   offs   = (int*)  alloc((size_t)(N_NODES + 1) * 4);
    int*   part   = (int*)  alloc(256 * 4);
    int*   csr_src= (int*)  alloc((size_t)ETOT * 4);
    int*   csr_eid= (int*)  alloc((size_t)ETOT * 4);

    const int T = 256;
    // ---- CSR build + init + weight prep ----
    k_init<<<dim3((NH8 + T - 1) / T), dim3(T), 0, stream>>>(degi, cursor, degf, den1, den2);
    k_deg<<<dim3((ETOT + T - 1) / T), dim3(T), 0, stream>>>(ei, ew, degi, degf);
    k_scan_a<<<dim3(NCHUNK), dim3(256), 0, stream>>>(degi, part);
    k_scan_b<<<dim3(1), dim3(256), 0, stream>>>(part);
    k_scan_c<<<dim3(NCHUNK), dim3(256), 0, stream>>>(degi, part, offs);
    k_scatter<<<dim3((ETOT + T - 1) / T), dim3(T), 0, stream>>>(ei, offs, cursor, csr_src, csr_eid);
    k_fold<<<dim3(1), dim3(128), 0, stream>>>(W1, a_src1, a_dst1, as1f, ad1f);
    k_packW2<<<dim3((HC1 * HC2 + T - 1) / T), dim3(T), 0, stream>>>(W2, W2T);

    // ---- GAT layer 1 (linearity trick: aggregate x, then expand) ----
    k_es1<<<dim3((NH8 + T - 1) / T), dim3(T), 0, stream>>>(x, as1f, ad1f, es1, ed1);
    k_edge_soft<<<dim3((ETOT * HEADS + T - 1) / T), dim3(T), 0, stream>>>(ei, es1, ed1, ebuf, den1);
    k_agg_x<<<dim3((NH8 + T - 1) / T), dim3(T), 0, stream>>>(x, ebuf, den1, offs, csr_src, csr_eid, aggx);
    k_expand<<<dim3(N_NODES), dim3(HC1), 0, stream>>>(aggx, W1, b1, x2bf);

    // ---- GAT layer 2 ----
    k_gemm_mfma<<<dim3(MPAD / 64, HC2 / 64), dim3(256), 0, stream>>>(
        (const short*)x2bf, (const short*)W2T, h2);
    k_es_ed<C2><<<dim3((NH8 + T - 1) / T), dim3(T), 0, stream>>>(h2, a_src2, a_dst2, es2, ed2);
    k_edge_soft<<<dim3((ETOT * HEADS + T - 1) / T), dim3(T), 0, stream>>>(ei, es2, ed2, ebuf, den2);
    k_gat_agg<C2><<<dim3(N_NODES), dim3(HC2), 0, stream>>>(h2, ebuf, den2, offs, csr_src, csr_eid, b2, x3);

    // ---- GCN + FC + sigmoid ----
    k_hg<<<dim3((N_NODES + 15) / 16), dim3(256), 0, stream>>>(x3, Wg, hg);
    k_gcn_out<<<dim3((N_NODES + 15) / 16), dim3(256), 0, stream>>>(
        hg, ew, degf, offs, csr_src, csr_eid, bg, Wfc, bfc, out);
}

// Round 3
// 487.221 us; speedup vs baseline: 2.0263x; 1.2802x over previous
//
#include <hip/hip_runtime.h>
#include <hip/hip_bf16.h>
#include <float.h>
#include <math.h>

#define N_NODES 50000
#define N_EDGES 400000
#define ETOT    (N_EDGES + N_NODES)   // 450000
#define F_IN    5
#define HEADS   8
#define C1      64
#define C2      32
#define C3      16
#define HC1     (HEADS * C1)          // 512
#define HC2     (HEADS * C2)          // 256
#define NEG_SLOPE 0.2f
#define NCHUNK  ((N_NODES + 255) / 256)  // 196
#define NH8     (N_NODES * HEADS)        // 400000
#define MPAD    (((N_NODES + 63) / 64) * 64)  // 50048 rows for MFMA GEMM

typedef short bf16x8 __attribute__((ext_vector_type(8)));
typedef float f32x4  __attribute__((ext_vector_type(4)));
typedef unsigned short ushort_t;

__device__ __forceinline__ float eluf(float x) {
    return x > 0.f ? x : (expf(x) - 1.f);
}
__device__ __forceinline__ float bf2f(unsigned short u) {
    union { unsigned int i; float f; } v; v.i = ((unsigned int)u) << 16; return v.f;
}
__device__ __forceinline__ unsigned short f2bf(float f) {
    __hip_bfloat16 b = __float2bfloat16(f);
    return *(unsigned short*)&b;
}

// ---------------- init: zero counters ----------------------------------
__global__ void k_init(int* degi, int* cursor, float* degf) {
    int i = blockIdx.x * blockDim.x + threadIdx.x;
    if (i < N_NODES) { degi[i] = 0; cursor[i] = 0; degf[i] = 0.f; }
}

// ---------------- degree histogram (int count + weighted for GCN) ------
__global__ void k_deg(const int* __restrict__ ei, const float* __restrict__ ew,
                      int* degi, float* degf) {
    int i = blockIdx.x * blockDim.x + threadIdx.x;
    if (i >= ETOT) return;
    int d   = (i < N_EDGES) ? ei[N_EDGES + i] : (i - N_EDGES);
    float w = (i < N_EDGES) ? ew[i] : 1.f;
    atomicAdd(&degi[d], 1);
    atomicAdd(&degf[d], w);
}

// ---------------- 3-kernel exclusive scan over deg[N] ------------------
__global__ void k_scan_a(const int* __restrict__ deg, int* __restrict__ part) {
    __shared__ int lds[256];
    int t = threadIdx.x;
    int i = blockIdx.x * 256 + t;
    lds[t] = (i < N_NODES) ? deg[i] : 0;
    __syncthreads();
    for (int off = 128; off >= 1; off >>= 1) {
        if (t < off) lds[t] += lds[t + off];
        __syncthreads();
    }
    if (t == 0) part[blockIdx.x] = lds[0];
}

__global__ void k_scan_b(int* part) {
    __shared__ int lds[256];
    int t = threadIdx.x;
    int v = (t < NCHUNK) ? part[t] : 0;
    lds[t] = v;
    __syncthreads();
    for (int off = 1; off < 256; off <<= 1) {
        int x = (t >= off) ? lds[t - off] : 0;
        __syncthreads();
        lds[t] += x;
        __syncthreads();
    }
    if (t < NCHUNK) part[t] = lds[t] - v;
}

__global__ void k_scan_c(const int* __restrict__ deg, const int* __restrict__ part,
                         int* __restrict__ offs) {
    __shared__ int lds[256];
    int t = threadIdx.x;
    int i = blockIdx.x * 256 + t;
    int v = (i < N_NODES) ? deg[i] : 0;
    lds[t] = v;
    __syncthreads();
    for (int off = 1; off < 256; off <<= 1) {
        int x = (t >= off) ? lds[t - off] : 0;
        __syncthreads();
        lds[t] += x;
        __syncthreads();
    }
    int excl = part[blockIdx.x] + lds[t] - v;
    if (i < N_NODES) offs[i] = excl;
    if (i == N_NODES - 1) offs[N_NODES] = excl + v;
}

// ---------------- scatter edges into CSR-by-dst (int2 {src,eid}) -------
__global__ void k_scatter(const int* __restrict__ ei, const int* __restrict__ offs,
                          int* cursor, int2* __restrict__ csr) {
    int i = blockIdx.x * blockDim.x + threadIdx.x;
    if (i >= ETOT) return;
    int s, d;
    if (i < N_EDGES) { s = ei[i]; d = ei[N_EDGES + i]; }
    else             { s = d = i - N_EDGES; }
    int pos = offs[d] + atomicAdd(&cursor[d], 1);
    csr[pos] = make_int2(s, i);
}

// ---------------- fold W1 into attention vectors: as1f[h,f] ------------
__global__ void k_fold(const float* __restrict__ W1,
                       const float* __restrict__ a_src1, const float* __restrict__ a_dst1,
                       float* __restrict__ as1f, float* __restrict__ ad1f) {
    int idx = threadIdx.x;
    if (idx >= HEADS * F_IN) return;
    int h = idx / F_IN, f = idx % F_IN;
    float s = 0.f, d = 0.f;
    for (int c = 0; c < C1; c++) {
        float w = W1[f * HC1 + h * C1 + c];
        s += w * a_src1[h * C1 + c];
        d += w * a_dst1[h * C1 + c];
    }
    as1f[idx] = s;
    ad1f[idx] = d;
}

// ---------------- es1/ed1 directly from x ------------------------------
__global__ void k_es1(const float* __restrict__ x,
                      const float* __restrict__ as1f, const float* __restrict__ ad1f,
                      float* __restrict__ es, float* __restrict__ ed) {
    int g = blockIdx.x * blockDim.x + threadIdx.x;
    if (g >= NH8) return;
    int n = g >> 3, h = g & 7;
    float vs = 0.f, vd = 0.f;
#pragma unroll
    for (int f = 0; f < F_IN; f++) {
        float xv = x[n * F_IN + f];
        vs += xv * as1f[h * F_IN + f];
        vd += xv * ad1f[h * F_IN + f];
    }
    es[g] = vs;
    ed[g] = vd;
}

// -------- edge softmax numerator (all 8 heads per thread, no atomics) --
__global__ void k_edge_soft(const int* __restrict__ ei,
                            const float* __restrict__ es, const float* __restrict__ ed,
                            float* __restrict__ ebuf) {
    int i = blockIdx.x * blockDim.x + threadIdx.x;
    if (i >= ETOT) return;
    int s, d;
    if (i < N_EDGES) { s = ei[i]; d = ei[N_EDGES + i]; }
    else             { s = d = i - N_EDGES; }
    float4 es0 = *(const float4*)(es + s * HEADS);
    float4 es1 = *(const float4*)(es + s * HEADS + 4);
    float4 ed0 = *(const float4*)(ed + d * HEADS);
    float4 ed1 = *(const float4*)(ed + d * HEADS + 4);
    float v[8] = {es0.x + ed0.x, es0.y + ed0.y, es0.z + ed0.z, es0.w + ed0.w,
                  es1.x + ed1.x, es1.y + ed1.y, es1.z + ed1.z, es1.w + ed1.w};
    float4 o0, o1;
#pragma unroll
    for (int h = 0; h < 8; h++) {
        float t = v[h] > 0.f ? v[h] : NEG_SLOPE * v[h];
        v[h] = expf(t);
    }
    o0 = make_float4(v[0], v[1], v[2], v[3]);
    o1 = make_float4(v[4], v[5], v[6], v[7]);
    *(float4*)(ebuf + (size_t)i * HEADS)     = o0;
    *(float4*)(ebuf + (size_t)i * HEADS + 4) = o1;
}

// -------- layer-1 aggregation of raw x per (dst, head), den inline -----
__global__ void k_agg_x(const float* __restrict__ x, const float* __restrict__ ebuf,
                        const int* __restrict__ offs, const int2* __restrict__ csr,
                        float* __restrict__ aggx) {
    int g = blockIdx.x * blockDim.x + threadIdx.x;
    if (g >= NH8) return;
    int d = g >> 3, h = g & 7;
    int k0 = offs[d], k1 = offs[d + 1];
    float a0 = 0.f, a1 = 0.f, a2 = 0.f, a3 = 0.f, a4 = 0.f, exsum = 0.f;
    for (int k = k0; k < k1; k++) {
        int2 se = csr[k];
        float ex = ebuf[(size_t)se.y * HEADS + h];
        const float* xp = x + se.x * F_IN;
        a0 += ex * xp[0];
        a1 += ex * xp[1];
        a2 += ex * xp[2];
        a3 += ex * xp[3];
        a4 += ex * xp[4];
        exsum += ex;
    }
    float inv = 1.f / (exsum + 1e-16f);
    aggx[0 * NH8 + g] = a0 * inv;
    aggx[1 * NH8 + g] = a1 * inv;
    aggx[2 * NH8 + g] = a2 * inv;
    aggx[3 * NH8 + g] = a3 * inv;
    aggx[4 * NH8 + g] = a4 * inv;
}

// -------- expand aggx (N,8,5) @ W1 -> x2 = elu(. + b1), store bf16 -----
__global__ __launch_bounds__(512) void k_expand(const float* __restrict__ aggx,
                                                const float* __restrict__ W1,
                                                const float* __restrict__ b1,
                                                ushort_t* __restrict__ x2bf) {
    int d = blockIdx.x;
    int t = threadIdx.x;       // t = h*64 + c
    int h = t >> 6;
    int g = d * HEADS + h;
    float acc = b1[t];
#pragma unroll
    for (int f = 0; f < F_IN; f++)
        acc += aggx[f * NH8 + g] * W1[f * HC1 + t];
    acc = eluf(acc);
    x2bf[(size_t)d * HC1 + t] = f2bf(acc);
}

// ---------------- pack W2 (512x256 f32) -> W2T (256x512 bf16) ----------
__global__ void k_packW2(const float* __restrict__ W2, ushort_t* __restrict__ W2T) {
    int idx = blockIdx.x * blockDim.x + threadIdx.x;
    if (idx >= HC1 * HC2) return;
    int k = idx / HC2, n = idx % HC2;
    W2T[(size_t)n * HC1 + k] = f2bf(W2[idx]);
}

// ---------------- bf16 MFMA GEMM: h2bf[M,256] = x2bf[M,512] @ W2T^T ----
__global__ __launch_bounds__(256) void k_gemm_mfma(const short* __restrict__ A,
                                                   const short* __restrict__ B,
                                                   ushort_t* __restrict__ C) {
    int wave = threadIdx.x >> 6;
    int lane = threadIdx.x & 63;
    int lo   = lane & 15;
    int quad = lane >> 4;
    int m0   = blockIdx.x * 64 + wave * 16;
    int col0 = blockIdx.y * 64;
    const short* ap = A + (size_t)(m0 + lo) * HC1 + quad * 8;
    const short* bp = B + (size_t)(col0 + lo) * HC1 + quad * 8;
    f32x4 acc0 = {0.f, 0.f, 0.f, 0.f};
    f32x4 acc1 = {0.f, 0.f, 0.f, 0.f};
    f32x4 acc2 = {0.f, 0.f, 0.f, 0.f};
    f32x4 acc3 = {0.f, 0.f, 0.f, 0.f};
#pragma unroll
    for (int k0 = 0; k0 < HC1; k0 += 32) {
        bf16x8 af = *(const bf16x8*)(ap + k0);
        bf16x8 b0 = *(const bf16x8*)(bp + 0 * 16 * HC1 + k0);
        bf16x8 b1 = *(const bf16x8*)(bp + 1 * 16 * HC1 + k0);
        bf16x8 b2 = *(const bf16x8*)(bp + 2 * 16 * HC1 + k0);
        bf16x8 b3 = *(const bf16x8*)(bp + 3 * 16 * HC1 + k0);
        acc0 = __builtin_amdgcn_mfma_f32_16x16x32_bf16(af, b0, acc0, 0, 0, 0);
        acc1 = __builtin_amdgcn_mfma_f32_16x16x32_bf16(af, b1, acc1, 0, 0, 0);
        acc2 = __builtin_amdgcn_mfma_f32_16x16x32_bf16(af, b2, acc2, 0, 0, 0);
        acc3 = __builtin_amdgcn_mfma_f32_16x16x32_bf16(af, b3, acc3, 0, 0, 0);
    }
    int colw = col0 + lo;
#pragma unroll
    for (int r = 0; r < 4; r++) {
        int row = m0 + quad * 4 + r;
        if (row < N_NODES) {
            C[(size_t)row * HC2 + colw +  0] = f2bf(acc0[r]);
            C[(size_t)row * HC2 + colw + 16] = f2bf(acc1[r]);
            C[(size_t)row * HC2 + colw + 32] = f2bf(acc2[r]);
            C[(size_t)row * HC2 + colw + 48] = f2bf(acc3[r]);
        }
    }
}

// ---------------- es/ed for layer 2 (bf16 h2) --------------------------
__global__ void k_es_ed(const ushort_t* __restrict__ hin,
                        const float* __restrict__ a_src, const float* __restrict__ a_dst,
                        float* __restrict__ es, float* __restrict__ ed) {
    int g = blockIdx.x * blockDim.x + threadIdx.x;
    if (g >= NH8) return;
    int n = g >> 3, h = g & 7;
    const ushort_t* hp = hin + (size_t)n * HC2 + h * C2;
    float vs = 0.f, vd = 0.f;
#pragma unroll
    for (int q = 0; q < 4; q++) {
        uint4 raw = *(const uint4*)(hp + q * 8);
        unsigned int ws[4] = {raw.x, raw.y, raw.z, raw.w};
#pragma unroll
        for (int j = 0; j < 4; j++) {
            float v0 = bf2f((unsigned short)(ws[j] & 0xffff));
            float v1 = bf2f((unsigned short)(ws[j] >> 16));
            int c = q * 8 + j * 2;
            vs += v0 * a_src[h * C2 + c]     + v1 * a_src[h * C2 + c + 1];
            vd += v0 * a_dst[h * C2 + c]     + v1 * a_dst[h * C2 + c + 1];
        }
    }
    es[g] = vs;
    ed[g] = vd;
}

// -------- layer-2 GAT aggregation: wave per dst, ushort4 loads ---------
__global__ __launch_bounds__(256) void k_gat_agg2(const ushort_t* __restrict__ h2bf,
                                                  const float* __restrict__ ebuf,
                                                  const int* __restrict__ offs,
                                                  const int2* __restrict__ csr,
                                                  const float* __restrict__ b2,
                                                  ushort_t* __restrict__ x3bf) {
    int wave = threadIdx.x >> 6;
    int lane = threadIdx.x & 63;
    int d = blockIdx.x * 4 + wave;
    if (d >= N_NODES) return;
    int c4 = lane * 4;            // 4 channels per lane
    int h  = lane >> 3;           // head = c4/32
    int k0 = offs[d], k1 = offs[d + 1];
    float acc0 = 0.f, acc1 = 0.f, acc2 = 0.f, acc3 = 0.f, exsum = 0.f;
    int k = k0;
    for (; k + 1 < k1; k += 2) {
        int2 e0 = csr[k];
        int2 e1 = csr[k + 1];
        float x0 = ebuf[(size_t)e0.y * HEADS + h];
        float x1 = ebuf[(size_t)e1.y * HEADS + h];
        ushort4 v0 = *(const ushort4*)(h2bf + (size_t)e0.x * HC2 + c4);
        ushort4 v1 = *(const ushort4*)(h2bf + (size_t)e1.x * HC2 + c4);
        acc0 += x0 * bf2f(v0.x) + x1 * bf2f(v1.x);
        acc1 += x0 * bf2f(v0.y) + x1 * bf2f(v1.y);
        acc2 += x0 * bf2f(v0.z) + x1 * bf2f(v1.z);
        acc3 += x0 * bf2f(v0.w) + x1 * bf2f(v1.w);
        exsum += x0 + x1;
    }
    if (k < k1) {
        int2 e0 = csr[k];
        float x0 = ebuf[(size_t)e0.y * HEADS + h];
        ushort4 v0 = *(const ushort4*)(h2bf + (size_t)e0.x * HC2 + c4);
        acc0 += x0 * bf2f(v0.x);
        acc1 += x0 * bf2f(v0.y);
        acc2 += x0 * bf2f(v0.z);
        acc3 += x0 * bf2f(v0.w);
        exsum += x0;
    }
    float inv = 1.f / (exsum + 1e-16f);
    float4 bias = *(const float4*)(b2 + c4);
    ushort4 o;
    o.x = f2bf(eluf(acc0 * inv + bias.x));
    o.y = f2bf(eluf(acc1 * inv + bias.y));
    o.z = f2bf(eluf(acc2 * inv + bias.z));
    o.w = f2bf(eluf(acc3 * inv + bias.w));
    *(ushort4*)(x3bf + (size_t)d * HC2 + c4) = o;
}

// ---------------- hg = x3 @ Wg  (N,256)@(256,16), bf16 x3 --------------
__global__ __launch_bounds__(256) void k_hg(const ushort_t* __restrict__ x3bf,
                                            const float* __restrict__ Wg,
                                            float* __restrict__ hg) {
    __shared__ float xs[16 * HC2];
    int n0 = blockIdx.x * 16;
    int t  = threadIdx.x;
    for (int q = t; q < 16 * HC2 / 4; q += 256) {
        int r  = q >> 6;           // row within tile (64 ushort4 per row)
        int cc = (q & 63) * 4;
        int n  = n0 + r;
        ushort4 v = make_ushort4(0, 0, 0, 0);
        if (n < N_NODES) v = *(const ushort4*)(x3bf + (size_t)n * HC2 + cc);
        xs[r * HC2 + cc + 0] = bf2f(v.x);
        xs[r * HC2 + cc + 1] = bf2f(v.y);
        xs[r * HC2 + cc + 2] = bf2f(v.z);
        xs[r * HC2 + cc + 3] = bf2f(v.w);
    }
    __syncthreads();
    int r = t >> 4, c = t & 15;
    float acc = 0.f;
#pragma unroll 4
    for (int k = 0; k < HC2; k++) acc += xs[r * HC2 + k] * Wg[k * C3 + c];
    int n = n0 + r;
    if (n < N_NODES) hg[(size_t)n * C3 + c] = acc;
}

// ---------------- GCN aggregate + ELU + FC + sigmoid (fused) -----------
__global__ __launch_bounds__(256) void k_gcn_out(const float* __restrict__ hg,
                                                 const float* __restrict__ ew,
                                                 const float* __restrict__ degf,
                                                 const int* __restrict__ offs,
                                                 const int2* __restrict__ csr,
                                                 const float* __restrict__ bg,
                                                 const float* __restrict__ Wfc,
                                                 const float* __restrict__ bfc,
                                                 float* __restrict__ out) {
    int t = threadIdx.x;
    int r = t >> 4, c = t & 15;
    int d = blockIdx.x * 16 + r;
    float val = 0.f;
    if (d < N_NODES) {
        float dd = degf[d];
        float dinv_d = dd > 0.f ? rsqrtf(dd) : 0.f;
        int k0 = offs[d], k1 = offs[d + 1];
        float acc = 0.f;
        for (int k = k0; k < k1; k++) {
            int2 se = csr[k];
            float w = (se.y < N_EDGES) ? ew[se.y] : 1.f;
            float ds_ = degf[se.x];
            float dinv_s = ds_ > 0.f ? rsqrtf(ds_) : 0.f;
            acc += hg[(size_t)se.x * C3 + c] * (dinv_s * w * dinv_d);
        }
        val = eluf(acc + bg[c]);
    }
    float z = val * Wfc[c];
#pragma unroll
    for (int off = 8; off >= 1; off >>= 1) z += __shfl_xor(z, off, 16);
    if (c == 0 && d < N_NODES) out[d] = 1.f / (1.f + expf(-(z + bfc[0])));
}

// =======================================================================
extern "C" void kernel_launch(void* const* d_in, const int* in_sizes, int n_in,
                              void* d_out, int out_size, void* d_ws, size_t ws_size,
                              hipStream_t stream) {
    const float* x       = (const float*)d_in[0];
    const int*   ei      = (const int*)  d_in[1];
    const float* ew      = (const float*)d_in[2];
    const float* W1      = (const float*)d_in[3];
    const float* a_src1  = (const float*)d_in[4];
    const float* a_dst1  = (const float*)d_in[5];
    const float* b1      = (const float*)d_in[6];
    const float* W2      = (const float*)d_in[7];
    const float* a_src2  = (const float*)d_in[8];
    const float* a_dst2  = (const float*)d_in[9];
    const float* b2      = (const float*)d_in[10];
    const float* Wg      = (const float*)d_in[11];
    const float* bg      = (const float*)d_in[12];
    const float* Wfc     = (const float*)d_in[13];
    const float* bfc     = (const float*)d_in[14];
    float* out = (float*)d_out;

    char* w = (char*)d_ws;
    size_t off = 0;
    auto alloc = [&](size_t bytes) -> void* {
        void* p = w + off;
        off = (off + bytes + 255) & ~(size_t)255;
        return p;
    };
    ushort_t* x2bf = (ushort_t*)alloc((size_t)MPAD * HC1 * 2);
    ushort_t* W2T  = (ushort_t*)alloc((size_t)HC2 * HC1 * 2);
    ushort_t* h2bf = (ushort_t*)alloc((size_t)N_NODES * HC2 * 2);
    ushort_t* x3bf = (ushort_t*)alloc((size_t)N_NODES * HC2 * 2);
    float* hg     = (float*)alloc((size_t)N_NODES * C3 * 4);
    float* ebuf   = (float*)alloc((size_t)ETOT * HEADS * 4);
    float* aggx   = (float*)alloc((size_t)F_IN * NH8 * 4);
    float* es1    = (float*)alloc((size_t)NH8 * 4);
    float* ed1    = (float*)alloc((size_t)NH8 * 4);
    float* es2    = (float*)alloc((size_t)NH8 * 4);
    float* ed2    = (float*)alloc((size_t)NH8 * 4);
    float* as1f   = (float*)alloc((size_t)HEADS * F_IN * 4);
    float* ad1f   = (float*)alloc((size_t)HEADS * F_IN * 4);
    float* degf   = (float*)alloc((size_t)N_NODES * 4);
    int*   degi   = (int*)  alloc((size_t)N_NODES * 4);
    int*   cursor = (int*)  alloc((size_t)N_NODES * 4);
    int*   offs   = (int*)  alloc((size_t)(N_NODES + 1) * 4);
    int*   part   = (int*)  alloc(256 * 4);
    int2*  csr    = (int2*) alloc((size_t)ETOT * 8);

    const int T = 256;
    // ---- CSR build + init + weight prep ----
    k_init<<<dim3((N_NODES + T - 1) / T), dim3(T), 0, stream>>>(degi, cursor, degf);
    k_deg<<<dim3((ETOT + T - 1) / T), dim3(T), 0, stream>>>(ei, ew, degi, degf);
    k_scan_a<<<dim3(NCHUNK), dim3(256), 0, stream>>>(degi, part);
    k_scan_b<<<dim3(1), dim3(256), 0, stream>>>(part);
    k_scan_c<<<dim3(NCHUNK), dim3(256), 0, stream>>>(degi, part, offs);
    k_scatter<<<dim3((ETOT + T - 1) / T), dim3(T), 0, stream>>>(ei, offs, cursor, csr);
    k_fold<<<dim3(1), dim3(128), 0, stream>>>(W1, a_src1, a_dst1, as1f, ad1f);
    k_packW2<<<dim3((HC1 * HC2 + T - 1) / T), dim3(T), 0, stream>>>(W2, W2T);

    // ---- GAT layer 1 (linearity trick) ----
    k_es1<<<dim3((NH8 + T - 1) / T), dim3(T), 0, stream>>>(x, as1f, ad1f, es1, ed1);
    k_edge_soft<<<dim3((ETOT + T - 1) / T), dim3(T), 0, stream>>>(ei, es1, ed1, ebuf);
    k_agg_x<<<dim3((NH8 + T - 1) / T), dim3(T), 0, stream>>>(x, ebuf, offs, csr, aggx);
    k_expand<<<dim3(N_NODES), dim3(HC1), 0, stream>>>(aggx, W1, b1, x2bf);

    // ---- GAT layer 2 ----
    k_gemm_mfma<<<dim3(MPAD / 64, HC2 / 64), dim3(256), 0, stream>>>(
        (const short*)x2bf, (const short*)W2T, h2bf);
    k_es_ed<<<dim3((NH8 + T - 1) / T), dim3(T), 0, stream>>>(h2bf, a_src2, a_dst2, es2, ed2);
    k_edge_soft<<<dim3((ETOT + T - 1) / T), dim3(T), 0, stream>>>(ei, es2, ed2, ebuf);
    k_gat_agg2<<<dim3((N_NODES + 3) / 4), dim3(256), 0, stream>>>(h2bf, ebuf, offs, csr, b2, x3bf);

    // ---- GCN + FC + sigmoid ----
    k_hg<<<dim3((N_NODES + 15) / 16), dim3(256), 0, stream>>>(x3bf, Wg, hg);
    k_gcn_out<<<dim3((N_NODES + 15) / 16), dim3(256), 0, stream>>>(
        hg, ew, degf, offs, csr, bg, Wfc, bfc, out);
}

// Round 4
// 421.535 us; speedup vs baseline: 2.3421x; 1.1558x over previous
//
#include <hip/hip_runtime.h>
#include <hip/hip_bf16.h>
#include <float.h>
#include <math.h>

#define N_NODES 50000
#define N_EDGES 400000
#define ETOT    (N_EDGES + N_NODES)   // 450000
#define F_IN    5
#define HEADS   8
#define C1      64
#define C2      32
#define C3      16
#define HC1     (HEADS * C1)          // 512
#define HC2     (HEADS * C2)          // 256
#define NEG_SLOPE 0.2f
#define NCHUNK  ((N_NODES + 255) / 256)  // 196
#define NH8     (N_NODES * HEADS)        // 400000
#define MPAD    (((N_NODES + 63) / 64) * 64)  // 50048 rows for MFMA GEMM
#define GCOLS   (HC2 + 16)            // 272: 256 h2 cols + 8 es + 8 ed
#define BSTR    40                    // LDS k-stride (elems): 16B-aligned, bank-spread

typedef short bf16x8 __attribute__((ext_vector_type(8)));
typedef float f32x4  __attribute__((ext_vector_type(4)));
typedef unsigned short ushort_t;

__device__ __forceinline__ float eluf(float x) {
    return x > 0.f ? x : (expf(x) - 1.f);
}
__device__ __forceinline__ float bf2f(unsigned short u) {
    union { unsigned int i; float f; } v; v.i = ((unsigned int)u) << 16; return v.f;
}
__device__ __forceinline__ unsigned short f2bf(float f) {
    __hip_bfloat16 b = __float2bfloat16(f);
    return *(unsigned short*)&b;
}

// ---------------- init: zero counters ----------------------------------
__global__ void k_init(int* degi, int* cursor, float* degf) {
    int i = blockIdx.x * blockDim.x + threadIdx.x;
    if (i < N_NODES) { degi[i] = 0; cursor[i] = 0; degf[i] = 0.f; }
}

// ---------------- degree histogram (int count + weighted for GCN) ------
__global__ void k_deg(const int* __restrict__ ei, const float* __restrict__ ew,
                      int* degi, float* degf) {
    int i = blockIdx.x * blockDim.x + threadIdx.x;
    if (i >= ETOT) return;
    int d   = (i < N_EDGES) ? ei[N_EDGES + i] : (i - N_EDGES);
    float w = (i < N_EDGES) ? ew[i] : 1.f;
    atomicAdd(&degi[d], 1);
    atomicAdd(&degf[d], w);
}

// ---------------- 3-kernel exclusive scan over deg[N] ------------------
__global__ void k_scan_a(const int* __restrict__ deg, int* __restrict__ part) {
    __shared__ int lds[256];
    int t = threadIdx.x;
    int i = blockIdx.x * 256 + t;
    lds[t] = (i < N_NODES) ? deg[i] : 0;
    __syncthreads();
    for (int off = 128; off >= 1; off >>= 1) {
        if (t < off) lds[t] += lds[t + off];
        __syncthreads();
    }
    if (t == 0) part[blockIdx.x] = lds[0];
}

__global__ void k_scan_b(int* part) {
    __shared__ int lds[256];
    int t = threadIdx.x;
    int v = (t < NCHUNK) ? part[t] : 0;
    lds[t] = v;
    __syncthreads();
    for (int off = 1; off < 256; off <<= 1) {
        int x = (t >= off) ? lds[t - off] : 0;
        __syncthreads();
        lds[t] += x;
        __syncthreads();
    }
    if (t < NCHUNK) part[t] = lds[t] - v;
}

__global__ void k_scan_c(const int* __restrict__ deg, const int* __restrict__ part,
                         int* __restrict__ offs) {
    __shared__ int lds[256];
    int t = threadIdx.x;
    int i = blockIdx.x * 256 + t;
    int v = (i < N_NODES) ? deg[i] : 0;
    lds[t] = v;
    __syncthreads();
    for (int off = 1; off < 256; off <<= 1) {
        int x = (t >= off) ? lds[t - off] : 0;
        __syncthreads();
        lds[t] += x;
        __syncthreads();
    }
    int excl = part[blockIdx.x] + lds[t] - v;
    if (i < N_NODES) offs[i] = excl;
    if (i == N_NODES - 1) offs[N_NODES] = excl + v;
}

// ---------------- scatter edges into CSR-by-dst (int2 {src,eid}) -------
__global__ void k_scatter(const int* __restrict__ ei, const int* __restrict__ offs,
                          int* cursor, int2* __restrict__ csr) {
    int i = blockIdx.x * blockDim.x + threadIdx.x;
    if (i >= ETOT) return;
    int s, d;
    if (i < N_EDGES) { s = ei[i]; d = ei[N_EDGES + i]; }
    else             { s = d = i - N_EDGES; }
    int pos = offs[d] + atomicAdd(&cursor[d], 1);
    csr[pos] = make_int2(s, i);
}

// ---------------- fold W1 into attention vectors: as1f[h,f] ------------
__global__ void k_fold(const float* __restrict__ W1,
                       const float* __restrict__ a_src1, const float* __restrict__ a_dst1,
                       float* __restrict__ as1f, float* __restrict__ ad1f) {
    int idx = threadIdx.x;
    if (idx >= HEADS * F_IN) return;
    int h = idx / F_IN, f = idx % F_IN;
    float s = 0.f, d = 0.f;
    for (int c = 0; c < C1; c++) {
        float w = W1[f * HC1 + h * C1 + c];
        s += w * a_src1[h * C1 + c];
        d += w * a_dst1[h * C1 + c];
    }
    as1f[idx] = s;
    ad1f[idx] = d;
}

// ---------------- es1/ed1 directly from x ------------------------------
__global__ void k_es1(const float* __restrict__ x,
                      const float* __restrict__ as1f, const float* __restrict__ ad1f,
                      float* __restrict__ es, float* __restrict__ ed) {
    int g = blockIdx.x * blockDim.x + threadIdx.x;
    if (g >= NH8) return;
    int n = g >> 3, h = g & 7;
    float vs = 0.f, vd = 0.f;
#pragma unroll
    for (int f = 0; f < F_IN; f++) {
        float xv = x[n * F_IN + f];
        vs += xv * as1f[h * F_IN + f];
        vd += xv * ad1f[h * F_IN + f];
    }
    es[g] = vs;
    ed[g] = vd;
}

// -------- edge softmax numerator (all 8 heads per thread, no atomics) --
__global__ void k_edge_soft(const int* __restrict__ ei,
                            const float* __restrict__ es, const float* __restrict__ ed,
                            float* __restrict__ ebuf) {
    int i = blockIdx.x * blockDim.x + threadIdx.x;
    if (i >= ETOT) return;
    int s, d;
    if (i < N_EDGES) { s = ei[i]; d = ei[N_EDGES + i]; }
    else             { s = d = i - N_EDGES; }
    float4 es0 = *(const float4*)(es + s * HEADS);
    float4 es1 = *(const float4*)(es + s * HEADS + 4);
    float4 ed0 = *(const float4*)(ed + d * HEADS);
    float4 ed1 = *(const float4*)(ed + d * HEADS + 4);
    float v[8] = {es0.x + ed0.x, es0.y + ed0.y, es0.z + ed0.z, es0.w + ed0.w,
                  es1.x + ed1.x, es1.y + ed1.y, es1.z + ed1.z, es1.w + ed1.w};
#pragma unroll
    for (int h = 0; h < 8; h++) {
        float t = v[h] > 0.f ? v[h] : NEG_SLOPE * v[h];
        v[h] = expf(t);
    }
    *(float4*)(ebuf + (size_t)i * HEADS)     = make_float4(v[0], v[1], v[2], v[3]);
    *(float4*)(ebuf + (size_t)i * HEADS + 4) = make_float4(v[4], v[5], v[6], v[7]);
}

// -------- layer-1 aggregation of raw x per (dst, head), den inline -----
__global__ void k_agg_x(const float* __restrict__ x, const float* __restrict__ ebuf,
                        const int* __restrict__ offs, const int2* __restrict__ csr,
                        float* __restrict__ aggx) {
    int g = blockIdx.x * blockDim.x + threadIdx.x;
    if (g >= NH8) return;
    int d = g >> 3, h = g & 7;
    int k0 = offs[d], k1 = offs[d + 1];
    float a0 = 0.f, a1 = 0.f, a2 = 0.f, a3 = 0.f, a4 = 0.f, exsum = 0.f;
    for (int k = k0; k < k1; k++) {
        int2 se = csr[k];
        float ex = ebuf[(size_t)se.y * HEADS + h];
        const float* xp = x + se.x * F_IN;
        a0 += ex * xp[0];
        a1 += ex * xp[1];
        a2 += ex * xp[2];
        a3 += ex * xp[3];
        a4 += ex * xp[4];
        exsum += ex;
    }
    float inv = 1.f / (exsum + 1e-16f);
    aggx[0 * NH8 + g] = a0 * inv;
    aggx[1 * NH8 + g] = a1 * inv;
    aggx[2 * NH8 + g] = a2 * inv;
    aggx[3 * NH8 + g] = a3 * inv;
    aggx[4 * NH8 + g] = a4 * inv;
}

// -------- expand aggx (N,8,5) @ W1 -> x2 = elu(. + b1), store bf16 -----
__global__ __launch_bounds__(512) void k_expand(const float* __restrict__ aggx,
                                                const float* __restrict__ W1,
                                                const float* __restrict__ b1,
                                                ushort_t* __restrict__ x2bf) {
    int d = blockIdx.x;
    int t = threadIdx.x;       // t = h*64 + c
    int h = t >> 6;
    int g = d * HEADS + h;
    float acc = b1[t];
#pragma unroll
    for (int f = 0; f < F_IN; f++)
        acc += aggx[f * NH8 + g] * W1[f * HC1 + t];
    acc = eluf(acc);
    x2bf[(size_t)d * HC1 + t] = f2bf(acc);
}

// -------- pack W2X[272][512]: W2^T plus folded a_src2/a_dst2 rows ------
__global__ void k_packW2X(const float* __restrict__ W2,
                          const float* __restrict__ a_src2, const float* __restrict__ a_dst2,
                          ushort_t* __restrict__ W2X) {
    int idx = blockIdx.x * blockDim.x + threadIdx.x;
    if (idx >= GCOLS * HC1) return;
    int c = idx >> 9;       // output column 0..271
    int k = idx & 511;      // k index
    float v;
    if (c < HC2) {
        v = W2[(size_t)k * HC2 + c];
    } else {
        int h = (c - HC2) & 7;
        const float* av = (c < HC2 + 8) ? a_src2 : a_dst2;
        v = 0.f;
#pragma unroll 8
        for (int j = 0; j < C2; j++)
            v += W2[(size_t)k * HC2 + h * C2 + j] * av[h * C2 + j];
    }
    W2X[idx] = f2bf(v);
}

// ------ bf16 MFMA GEMM: block = 64 rows x 272 cols, B staged in LDS ----
// Writes h2bf (cols 0..255) + es2/ed2 (cols 256..271) in one pass.
__global__ __launch_bounds__(256) void k_gemm_mfma(const short* __restrict__ A,
                                                   const short* __restrict__ W2X,
                                                   ushort_t* __restrict__ h2bf,
                                                   float* __restrict__ es2,
                                                   float* __restrict__ ed2) {
    __shared__ short Bs[GCOLS * BSTR];   // 272*40*2 = 21760 B
    int t    = threadIdx.x;
    int wave = t >> 6;
    int lane = t & 63;
    int lo   = lane & 15;
    int quad = lane >> 4;
    int m0   = blockIdx.x * 64 + wave * 16;
    const short* ap = A + (size_t)(m0 + lo) * HC1 + quad * 8;
    f32x4 acc[17];
#pragma unroll
    for (int f = 0; f < 17; f++) acc[f] = (f32x4){0.f, 0.f, 0.f, 0.f};

    for (int k0 = 0; k0 < HC1; k0 += 32) {
        __syncthreads();
        // cooperative stage: 272 cols x 32 k (4 chunks of 16B per col)
        for (int idx = t; idx < GCOLS * 4; idx += 256) {
            int c = idx >> 2, q = idx & 3;
            *(bf16x8*)(Bs + c * BSTR + q * 8) =
                *(const bf16x8*)(W2X + (size_t)c * HC1 + k0 + q * 8);
        }
        __syncthreads();
        bf16x8 af = *(const bf16x8*)(ap + k0);
#pragma unroll
        for (int f = 0; f < 17; f++) {
            bf16x8 bfr = *(const bf16x8*)(Bs + (f * 16 + lo) * BSTR + quad * 8);
            acc[f] = __builtin_amdgcn_mfma_f32_16x16x32_bf16(af, bfr, acc[f], 0, 0, 0);
        }
    }
    // epilogue: h2 cols
#pragma unroll
    for (int f = 0; f < 16; f++) {
#pragma unroll
        for (int r = 0; r < 4; r++) {
            int row = m0 + quad * 4 + r;
            if (row < N_NODES)
                h2bf[(size_t)row * HC2 + f * 16 + lo] = f2bf(acc[f][r]);
        }
    }
    // epilogue: es2/ed2 cols (col 256+lo: lo<8 -> es head lo, else ed head lo-8)
#pragma unroll
    for (int r = 0; r < 4; r++) {
        int row = m0 + quad * 4 + r;
        if (row < N_NODES) {
            if (lo < 8) es2[row * HEADS + lo]       = acc[16][r];
            else        ed2[row * HEADS + (lo - 8)] = acc[16][r];
        }
    }
}

// -------- layer-2 GAT aggregation: wave per dst, ushort4 loads ---------
__global__ __launch_bounds__(256) void k_gat_agg2(const ushort_t* __restrict__ h2bf,
                                                  const float* __restrict__ ebuf,
                                                  const int* __restrict__ offs,
                                                  const int2* __restrict__ csr,
                                                  const float* __restrict__ b2,
                                                  ushort_t* __restrict__ x3bf) {
    int wave = threadIdx.x >> 6;
    int lane = threadIdx.x & 63;
    int d = blockIdx.x * 4 + wave;
    if (d >= N_NODES) return;
    int c4 = lane * 4;            // 4 channels per lane
    int h  = lane >> 3;           // head = c4/32
    int k0 = offs[d], k1 = offs[d + 1];
    float acc0 = 0.f, acc1 = 0.f, acc2 = 0.f, acc3 = 0.f, exsum = 0.f;
    int k = k0;
    for (; k + 1 < k1; k += 2) {
        int2 e0 = csr[k];
        int2 e1 = csr[k + 1];
        float x0 = ebuf[(size_t)e0.y * HEADS + h];
        float x1 = ebuf[(size_t)e1.y * HEADS + h];
        ushort4 v0 = *(const ushort4*)(h2bf + (size_t)e0.x * HC2 + c4);
        ushort4 v1 = *(const ushort4*)(h2bf + (size_t)e1.x * HC2 + c4);
        acc0 += x0 * bf2f(v0.x) + x1 * bf2f(v1.x);
        acc1 += x0 * bf2f(v0.y) + x1 * bf2f(v1.y);
        acc2 += x0 * bf2f(v0.z) + x1 * bf2f(v1.z);
        acc3 += x0 * bf2f(v0.w) + x1 * bf2f(v1.w);
        exsum += x0 + x1;
    }
    if (k < k1) {
        int2 e0 = csr[k];
        float x0 = ebuf[(size_t)e0.y * HEADS + h];
        ushort4 v0 = *(const ushort4*)(h2bf + (size_t)e0.x * HC2 + c4);
        acc0 += x0 * bf2f(v0.x);
        acc1 += x0 * bf2f(v0.y);
        acc2 += x0 * bf2f(v0.z);
        acc3 += x0 * bf2f(v0.w);
        exsum += x0;
    }
    float inv = 1.f / (exsum + 1e-16f);
    float4 bias = *(const float4*)(b2 + c4);
    ushort4 o;
    o.x = f2bf(eluf(acc0 * inv + bias.x));
    o.y = f2bf(eluf(acc1 * inv + bias.y));
    o.z = f2bf(eluf(acc2 * inv + bias.z));
    o.w = f2bf(eluf(acc3 * inv + bias.w));
    *(ushort4*)(x3bf + (size_t)d * HC2 + c4) = o;
}

// ---------------- hg = x3 @ Wg  (N,256)@(256,16), bf16 x3 --------------
__global__ __launch_bounds__(256) void k_hg(const ushort_t* __restrict__ x3bf,
                                            const float* __restrict__ Wg,
                                            float* __restrict__ hg) {
    __shared__ float xs[16 * HC2];
    int n0 = blockIdx.x * 16;
    int t  = threadIdx.x;
    for (int q = t; q < 16 * HC2 / 4; q += 256) {
        int r  = q >> 6;           // row within tile (64 ushort4 per row)
        int cc = (q & 63) * 4;
        int n  = n0 + r;
        ushort4 v = make_ushort4(0, 0, 0, 0);
        if (n < N_NODES) v = *(const ushort4*)(x3bf + (size_t)n * HC2 + cc);
        xs[r * HC2 + cc + 0] = bf2f(v.x);
        xs[r * HC2 + cc + 1] = bf2f(v.y);
        xs[r * HC2 + cc + 2] = bf2f(v.z);
        xs[r * HC2 + cc + 3] = bf2f(v.w);
    }
    __syncthreads();
    int r = t >> 4, c = t & 15;
    float acc = 0.f;
#pragma unroll 4
    for (int k = 0; k < HC2; k++) acc += xs[r * HC2 + k] * Wg[k * C3 + c];
    int n = n0 + r;
    if (n < N_NODES) hg[(size_t)n * C3 + c] = acc;
}

// ---------------- GCN aggregate + ELU + FC + sigmoid (fused) -----------
__global__ __launch_bounds__(256) void k_gcn_out(const float* __restrict__ hg,
                                                 const float* __restrict__ ew,
                                                 const float* __restrict__ degf,
                                                 const int* __restrict__ offs,
                                                 const int2* __restrict__ csr,
                                                 const float* __restrict__ bg,
                                                 const float* __restrict__ Wfc,
                                                 const float* __restrict__ bfc,
                                                 float* __restrict__ out) {
    int t = threadIdx.x;
    int r = t >> 4, c = t & 15;
    int d = blockIdx.x * 16 + r;
    float val = 0.f;
    if (d < N_NODES) {
        float dd = degf[d];
        float dinv_d = dd > 0.f ? rsqrtf(dd) : 0.f;
        int k0 = offs[d], k1 = offs[d + 1];
        float acc = 0.f;
        for (int k = k0; k < k1; k++) {
            int2 se = csr[k];
            float w = (se.y < N_EDGES) ? ew[se.y] : 1.f;
            float ds_ = degf[se.x];
            float dinv_s = ds_ > 0.f ? rsqrtf(ds_) : 0.f;
            acc += hg[(size_t)se.x * C3 + c] * (dinv_s * w * dinv_d);
        }
        val = eluf(acc + bg[c]);
    }
    float z = val * Wfc[c];
#pragma unroll
    for (int off = 8; off >= 1; off >>= 1) z += __shfl_xor(z, off, 16);
    if (c == 0 && d < N_NODES) out[d] = 1.f / (1.f + expf(-(z + bfc[0])));
}

// =======================================================================
extern "C" void kernel_launch(void* const* d_in, const int* in_sizes, int n_in,
                              void* d_out, int out_size, void* d_ws, size_t ws_size,
                              hipStream_t stream) {
    const float* x       = (const float*)d_in[0];
    const int*   ei      = (const int*)  d_in[1];
    const float* ew      = (const float*)d_in[2];
    const float* W1      = (const float*)d_in[3];
    const float* a_src1  = (const float*)d_in[4];
    const float* a_dst1  = (const float*)d_in[5];
    const float* b1      = (const float*)d_in[6];
    const float* W2      = (const float*)d_in[7];
    const float* a_src2  = (const float*)d_in[8];
    const float* a_dst2  = (const float*)d_in[9];
    const float* b2      = (const float*)d_in[10];
    const float* Wg      = (const float*)d_in[11];
    const float* bg      = (const float*)d_in[12];
    const float* Wfc     = (const float*)d_in[13];
    const float* bfc     = (const float*)d_in[14];
    float* out = (float*)d_out;

    char* w = (char*)d_ws;
    size_t off = 0;
    auto alloc = [&](size_t bytes) -> void* {
        void* p = w + off;
        off = (off + bytes + 255) & ~(size_t)255;
        return p;
    };
    ushort_t* x2bf = (ushort_t*)alloc((size_t)MPAD * HC1 * 2);
    ushort_t* W2X  = (ushort_t*)alloc((size_t)GCOLS * HC1 * 2);
    ushort_t* h2bf = (ushort_t*)alloc((size_t)N_NODES * HC2 * 2);
    ushort_t* x3bf = (ushort_t*)alloc((size_t)N_NODES * HC2 * 2);
    float* hg     = (float*)alloc((size_t)N_NODES * C3 * 4);
    float* ebuf   = (float*)alloc((size_t)ETOT * HEADS * 4);
    float* aggx   = (float*)alloc((size_t)F_IN * NH8 * 4);
    float* es1    = (float*)alloc((size_t)NH8 * 4);
    float* ed1    = (float*)alloc((size_t)NH8 * 4);
    float* es2    = (float*)alloc((size_t)NH8 * 4);
    float* ed2    = (float*)alloc((size_t)NH8 * 4);
    float* as1f   = (float*)alloc((size_t)HEADS * F_IN * 4);
    float* ad1f   = (float*)alloc((size_t)HEADS * F_IN * 4);
    float* degf   = (float*)alloc((size_t)N_NODES * 4);
    int*   degi   = (int*)  alloc((size_t)N_NODES * 4);
    int*   cursor = (int*)  alloc((size_t)N_NODES * 4);
    int*   offs   = (int*)  alloc((size_t)(N_NODES + 1) * 4);
    int*   part   = (int*)  alloc(256 * 4);
    int2*  csr    = (int2*) alloc((size_t)ETOT * 8);

    const int T = 256;
    // ---- CSR build + init + weight prep ----
    k_init<<<dim3((N_NODES + T - 1) / T), dim3(T), 0, stream>>>(degi, cursor, degf);
    k_deg<<<dim3((ETOT + T - 1) / T), dim3(T), 0, stream>>>(ei, ew, degi, degf);
    k_scan_a<<<dim3(NCHUNK), dim3(256), 0, stream>>>(degi, part);
    k_scan_b<<<dim3(1), dim3(256), 0, stream>>>(part);
    k_scan_c<<<dim3(NCHUNK), dim3(256), 0, stream>>>(degi, part, offs);
    k_scatter<<<dim3((ETOT + T - 1) / T), dim3(T), 0, stream>>>(ei, offs, cursor, csr);
    k_fold<<<dim3(1), dim3(128), 0, stream>>>(W1, a_src1, a_dst1, as1f, ad1f);
    k_packW2X<<<dim3((GCOLS * HC1 + T - 1) / T), dim3(T), 0, stream>>>(W2, a_src2, a_dst2, W2X);

    // ---- GAT layer 1 (linearity trick) ----
    k_es1<<<dim3((NH8 + T - 1) / T), dim3(T), 0, stream>>>(x, as1f, ad1f, es1, ed1);
    k_edge_soft<<<dim3((ETOT + T - 1) / T), dim3(T), 0, stream>>>(ei, es1, ed1, ebuf);
    k_agg_x<<<dim3((NH8 + T - 1) / T), dim3(T), 0, stream>>>(x, ebuf, offs, csr, aggx);
    k_expand<<<dim3(N_NODES), dim3(HC1), 0, stream>>>(aggx, W1, b1, x2bf);

    // ---- GAT layer 2 (GEMM also emits es2/ed2 via folded columns) ----
    k_gemm_mfma<<<dim3(MPAD / 64), dim3(256), 0, stream>>>(
        (const short*)x2bf, (const short*)W2X, h2bf, es2, ed2);
    k_edge_soft<<<dim3((ETOT + T - 1) / T), dim3(T), 0, stream>>>(ei, es2, ed2, ebuf);
    k_gat_agg2<<<dim3((N_NODES + 3) / 4), dim3(256), 0, stream>>>(h2bf, ebuf, offs, csr, b2, x3bf);

    // ---- GCN + FC + sigmoid ----
    k_hg<<<dim3((N_NODES + 15) / 16), dim3(256), 0, stream>>>(x3bf, Wg, hg);
    k_gcn_out<<<dim3((N_NODES + 15) / 16), dim3(256), 0, stream>>>(
        hg, ew, degf, offs, csr, bg, Wfc, bfc, out);
}